// Round 2
// baseline (115.946 us; speedup 1.0000x reference)
//
#include <hip/hip_runtime.h>
#include <hip/hip_bf16.h>

#define T_LEN   6000
#define F_DIM   80
#define NROWS   2560           // 32 * 80
#define CHUNK   256            // 64 lanes * 4 elems
#define NCHUNK  24             // 23 full chunks + 112-elem tail (112 = 28 lanes * 4)
#define DEPTH   8              // prefetch pipeline depth (8 KB in flight per wave)
#define FLOORV  1e-6f

// gfx950 hardware transcendentals (avoid glibc __exp2f/__log2f name collision)
__device__ __forceinline__ float hw_exp2(float x) { return __builtin_amdgcn_exp2f(x); }
__device__ __forceinline__ float hw_log2(float x) { return __builtin_amdgcn_logf(x); }

__device__ __forceinline__ float4 load_chunk(const float* __restrict__ p, int k, int lane) {
    int t = k * CHUNK + lane * 4;
    if (t < T_LEN) {
        // row base = row*6000 floats = 24000 B (16B-aligned), t % 4 == 0 -> aligned float4
        return *reinterpret_cast<const float4*>(p + t);
    }
    return make_float4(0.f, 0.f, 0.f, 0.f);
}

__device__ __forceinline__ float pcen_elem(float x, float m, float neg_a, float d,
                                           float inv_r, float droot) {
    float g = hw_exp2(neg_a * hw_log2(m + FLOORV));   // (FLOOR + ema)^(-a)
    float y = fmaf(x, g, d);                          // x/(FLOOR+ema)^a + d   (y >= d > 0 here)
    return hw_exp2(inv_r * hw_log2(y)) - droot;       // y^(1/r) - d^(1/r)
}

__global__ __launch_bounds__(256) void pcen_kernel(
    const float* __restrict__ x,
    const float* __restrict__ smooth,
    const float* __restrict__ alpha,
    const float* __restrict__ delta,
    const float* __restrict__ root,
    float* __restrict__ out)
{
    const int lane = threadIdx.x & 63;
    const int wave = threadIdx.x >> 6;
    const int row  = blockIdx.x * 4 + wave;           // grid = 640 blocks * 4 waves = 2560 rows
    if (row >= NROWS) return;
    const int f = row % F_DIM;

    // per-row parameters (wave-uniform)
    float s   = fminf(fmaxf(smooth[f], 0.f), 1.f);
    float c   = 1.f - s;
    float a   = fminf(alpha[f], 1.f);
    float d   = delta[f];
    float r   = fmaxf(root[f], 1.f);
    float inv_r = 1.f / r;
    float neg_a = -a;
    float droot = hw_exp2(inv_r * hw_log2(d));        // d^(1/r), d > 0 per problem

    // powers of c
    const float c1 = c, c2 = c * c, c3 = c2 * c, c4 = c2 * c2;
    float q0 = c4;                 // c^(4*1)
    float q1 = q0 * q0;            // c^(4*2)
    float q2 = q1 * q1;            // c^(4*4)
    float q3 = q2 * q2;            // c^(4*8)
    float q4 = q3 * q3;            // c^(4*16)
    float q5 = q4 * q4;            // c^(4*32)
    float c256 = q5 * q5;          // c^256 : full-chunk decay
    // c^(4*lane) via exp2(4*lane*log2 c); guard lane==0 against 0 * (-inf) when c==0
    float c4lane = (lane == 0) ? 1.0f : hw_exp2(4.0f * (float)lane * hw_log2(c));

    const float* __restrict__ px = x   + (size_t)row * T_LEN;
    float*       __restrict__ po = out + (size_t)row * T_LEN;

    // depth-8 software pipeline of chunk loads
    float4 v[DEPTH];
#pragma unroll
    for (int i = 0; i < DEPTH; ++i) v[i] = load_chunk(px, i, lane);

    // carry = m at t=-1; setting it to x[0] makes m0 = c*x0 + s*x0 = x0 (ref: ema[0]=x[0])
    float carry = px[0];

#pragma unroll
    for (int k = 0; k < NCHUNK; ++k) {
        float4 cur = v[k % DEPTH];
        if (k + DEPTH < NCHUNK) v[k % DEPTH] = load_chunk(px, k + DEPTH, lane);

        // local (per-lane) inclusive scan of 4 elements, as if m_in = 0
        float b0 = s * cur.x;
        float b1 = fmaf(c, b0, s * cur.y);
        float b2 = fmaf(c, b1, s * cur.z);
        float b3 = fmaf(c, b2, s * cur.w);

        // wave scan over lane carries. A-coefficients are the scalars q_k, so only
        // B needs combining: B_i = q_k * B_{i-2^k} + B_i  (lanes >= offset)
        float B = b3;
        {
            float Bu;
            Bu = __shfl_up(B, 1, 64);  if (lane >= 1)  B = fmaf(q0, Bu, B);
            Bu = __shfl_up(B, 2, 64);  if (lane >= 2)  B = fmaf(q1, Bu, B);
            Bu = __shfl_up(B, 4, 64);  if (lane >= 4)  B = fmaf(q2, Bu, B);
            Bu = __shfl_up(B, 8, 64);  if (lane >= 8)  B = fmaf(q3, Bu, B);
            Bu = __shfl_up(B, 16, 64); if (lane >= 16) B = fmaf(q4, Bu, B);
            Bu = __shfl_up(B, 32, 64); if (lane >= 32) B = fmaf(q5, Bu, B);
        }
        // exclusive prefix for this lane
        float Bex = __shfl_up(B, 1, 64);
        if (lane == 0) Bex = 0.f;
        float m_in = fmaf(c4lane, carry, Bex);

        // chunk carry update (do early so scheduler can overlap with pcen math)
        float B63 = __shfl(B, 63, 64);
        carry = fmaf(c256, carry, B63);

        // per-element EMA values
        float m0 = fmaf(c1, m_in, b0);
        float m1 = fmaf(c2, m_in, b1);
        float m2 = fmaf(c3, m_in, b2);
        float m3 = fmaf(c4, m_in, b3);

        float4 o;
        o.x = pcen_elem(cur.x, m0, neg_a, d, inv_r, droot);
        o.y = pcen_elem(cur.y, m1, neg_a, d, inv_r, droot);
        o.z = pcen_elem(cur.z, m2, neg_a, d, inv_r, droot);
        o.w = pcen_elem(cur.w, m3, neg_a, d, inv_r, droot);

        int t = k * CHUNK + lane * 4;
        if (t < T_LEN) {
            *reinterpret_cast<float4*>(po + t) = o;
        }
    }
}

extern "C" void kernel_launch(void* const* d_in, const int* in_sizes, int n_in,
                              void* d_out, int out_size, void* d_ws, size_t ws_size,
                              hipStream_t stream) {
    const float* x      = (const float*)d_in[0];
    const float* smooth = (const float*)d_in[1];
    const float* alpha  = (const float*)d_in[2];
    const float* delta  = (const float*)d_in[3];
    const float* root   = (const float*)d_in[4];
    float* out = (float*)d_out;

    dim3 grid(NROWS / 4);   // 640 blocks, 4 waves each -> 2560 waves, one per (B,F) row
    dim3 block(256);
    pcen_kernel<<<grid, block, 0, stream>>>(x, smooth, alpha, delta, root, out);
}